// Round 1
// baseline (428.762 us; speedup 1.0000x reference)
//
#include <hip/hip_runtime.h>

#define B_  4
#define S_  2048
#define D_  1024
#define H_  16
#define DH_ 64

typedef __attribute__((ext_vector_type(8))) short bf16x8;
typedef __attribute__((ext_vector_type(4))) float f32x4;
typedef __attribute__((ext_vector_type(4))) unsigned short u16x4;

__device__ __forceinline__ unsigned short f2bf(float f) {
  union { float f; unsigned int u; } x; x.f = f;
  unsigned int u = x.u;
  unsigned int r = (u + 0x7fffu + ((u >> 16) & 1u)) >> 16;  // RNE
  return (unsigned short)r;
}
__device__ __forceinline__ float bf2f(unsigned short b) {
  union { unsigned int u; float f; } x; x.u = ((unsigned int)b) << 16; return x.f;
}

// ---------------- mask fp32 -> bf16 ----------------
__global__ __launch_bounds__(256) void mconv_kernel(const float* __restrict__ m,
                                                    unsigned short* __restrict__ o) {
  const float4* m4 = (const float4*)m;
  u16x4* o4 = (u16x4*)o;
  const int n4 = (S_ * S_) / 4;
  for (int i = blockIdx.x * blockDim.x + threadIdx.x; i < n4; i += gridDim.x * blockDim.x) {
    float4 v = m4[i];
    u16x4 b = { f2bf(v.x), f2bf(v.y), f2bf(v.z), f2bf(v.w) };
    o4[i] = b;
  }
}

// ---------------- W (fp32 [k][n]) -> Wt (bf16 [n][k]) ----------------
__global__ __launch_bounds__(256) void wtrans_kernel(const float* __restrict__ W0,
                                                     const float* __restrict__ W1,
                                                     const float* __restrict__ W2,
                                                     unsigned short* __restrict__ Wt) {
  __shared__ float t[32][33];
  const int z = blockIdx.z;
  const float* W = (z == 0) ? W0 : ((z == 1) ? W1 : W2);
  unsigned short* O = Wt + (size_t)z * (D_ * D_);
  const int n0 = blockIdx.x * 32, k0 = blockIdx.y * 32;
  const int tx = threadIdx.x, ty = threadIdx.y;
#pragma unroll
  for (int i = 0; i < 4; i++) t[ty + i * 8][tx] = W[(size_t)(k0 + ty + i * 8) * D_ + n0 + tx];
  __syncthreads();
#pragma unroll
  for (int i = 0; i < 4; i++)
    O[(size_t)(n0 + ty + i * 8) * D_ + k0 + tx] = f2bf(t[tx][ty + i * 8]);
}

// ---------------- projection GEMM: Y(bf16) = X(fp32) @ W, via Wt ----------------
// 128x128 tile, BK=64, 4 waves each computing 64x64 (4x4 MFMA frags).
__global__ __launch_bounds__(256) void proj_kernel(const float* __restrict__ X0,
                                                   const float* __restrict__ X1,
                                                   const float* __restrict__ X2,
                                                   const unsigned short* __restrict__ Wt,
                                                   unsigned short* __restrict__ Y0) {
  __shared__ unsigned short Alds[128 * 72];  // [row][k], pad 8 -> 144B rows (16B aligned, 2-way free)
  __shared__ unsigned short Blds[128 * 72];  // [col][k] (= Wt rows)
  const int z = blockIdx.z;
  const float* X = (z == 0) ? X0 : ((z == 1) ? X1 : X2);
  const unsigned short* Wz = Wt + (size_t)z * (D_ * D_);
  unsigned short* Y = Y0 + (size_t)z * ((size_t)B_ * S_ * D_);

  const int tid = threadIdx.x;
  const int lane = tid & 63, w = tid >> 6;
  const int wr = w >> 1, wc = w & 1;
  const int l15 = lane & 15, lg = lane >> 4;
  const int r0 = blockIdx.y * 128, c0 = blockIdx.x * 128;

  f32x4 acc[4][4];
#pragma unroll
  for (int m = 0; m < 4; m++)
#pragma unroll
    for (int n = 0; n < 4; n++) acc[m][n] = (f32x4){0.f, 0.f, 0.f, 0.f};

  for (int kt = 0; kt < 16; ++kt) {
    __syncthreads();
    {
      const int rr = tid >> 4, cf = (tid & 15) * 4;
#pragma unroll
      for (int p = 0; p < 8; p++) {
        int row = rr + p * 16;
        float4 xv = *(const float4*)(X + (size_t)(r0 + row) * D_ + kt * 64 + cf);
        u16x4 bb = { f2bf(xv.x), f2bf(xv.y), f2bf(xv.z), f2bf(xv.w) };
        *(u16x4*)(&Alds[row * 72 + cf]) = bb;
      }
      const int rb = tid >> 3, cb = tid & 7;
#pragma unroll
      for (int p = 0; p < 4; p++) {
        int row = rb + p * 32;
        bf16x8 wv = *(const bf16x8*)(Wz + (size_t)(c0 + row) * D_ + kt * 64 + cb * 8);
        *(bf16x8*)(&Blds[row * 72 + cb * 8]) = wv;
      }
    }
    __syncthreads();

    bf16x8 af[4][2];
#pragma unroll
    for (int m = 0; m < 4; m++)
#pragma unroll
      for (int kc = 0; kc < 2; kc++)
        af[m][kc] = *(const bf16x8*)(&Alds[(wr * 64 + m * 16 + l15) * 72 + kc * 32 + lg * 8]);
#pragma unroll
    for (int n = 0; n < 4; n++) {
      bf16x8 bfr[2];
#pragma unroll
      for (int kc = 0; kc < 2; kc++)
        bfr[kc] = *(const bf16x8*)(&Blds[(wc * 64 + n * 16 + l15) * 72 + kc * 32 + lg * 8]);
#pragma unroll
      for (int m = 0; m < 4; m++)
#pragma unroll
        for (int kc = 0; kc < 2; kc++)
          acc[m][n] = __builtin_amdgcn_mfma_f32_16x16x32_bf16(af[m][kc], bfr[kc], acc[m][n], 0, 0, 0);
    }
  }

#pragma unroll
  for (int m = 0; m < 4; m++)
#pragma unroll
    for (int n = 0; n < 4; n++)
#pragma unroll
      for (int r = 0; r < 4; r++) {
        int row = r0 + wr * 64 + m * 16 + lg * 4 + r;  // C/D: row=(lane>>4)*4+reg
        int col = c0 + wc * 64 + n * 16 + l15;         // C/D: col=lane&15
        Y[(size_t)row * D_ + col] = f2bf(acc[m][n][r]);
      }
}

// ---------------- fused attention ----------------
// grid (S/64, H, B); 256 threads = 4 waves; wave w owns q-rows [q0+16w, q0+16w+16)
__global__ __launch_bounds__(256) void attn_kernel(const unsigned short* __restrict__ qh,
                                                   const unsigned short* __restrict__ kh,
                                                   const unsigned short* __restrict__ vh,
                                                   const unsigned short* __restrict__ mb,
                                                   float* __restrict__ out) {
  __shared__ unsigned short K_lds[64 * 72];   // [krow][d], pad 8
  __shared__ unsigned short V_lds[64 * 72];   // transposed [d][k], pad 8, XOR-swizzled
  __shared__ unsigned short P_lds[4 * 16 * 72];  // per-wave P re-layout buffer

  const int tid = threadIdx.x;
  const int lane = tid & 63, w = tid >> 6;
  const int l15 = lane & 15, lg = lane >> 4;
  const int q0 = blockIdx.x * 64;
  const int h = blockIdx.y, b = blockIdx.z;

  const size_t head_base = (size_t)b * S_ * D_ + h * DH_;

  // Q fragments (held in registers for all tiles): A row = lane&15
  bf16x8 aq[2];
  {
    int qr = q0 + w * 16 + l15;
#pragma unroll
    for (int kc = 0; kc < 2; kc++)
      aq[kc] = *(const bf16x8*)(qh + head_base + (size_t)qr * D_ + kc * 32 + lg * 8);
  }

  f32x4 o_acc[4];
#pragma unroll
  for (int dn = 0; dn < 4; dn++) o_acc[dn] = (f32x4){0.f, 0.f, 0.f, 0.f};
  float m_r[4], l_r[4];
#pragma unroll
  for (int r = 0; r < 4; r++) { m_r[r] = -INFINITY; l_r[r] = 0.f; }

  const int qrow = q0 + w * 16 + lg * 4;  // + r gives this lane's C-row
  unsigned short* pw = &P_lds[w * 16 * 72];

  for (int kt = 0; kt < 32; ++kt) {
    __syncthreads();
    {  // stage K (row-major) and V (transposed + swizzled)
      const int rr = tid >> 3, cc = tid & 7;
#pragma unroll
      for (int p = 0; p < 2; p++) {
        int row = rr + p * 32;
        size_t g = head_base + (size_t)(kt * 64 + row) * D_ + cc * 8;
        bf16x8 kv = *(const bf16x8*)(kh + g);
        *(bf16x8*)(&K_lds[row * 72 + cc * 8]) = kv;
        bf16x8 vv = *(const bf16x8*)(vh + g);
#pragma unroll
        for (int j = 0; j < 8; j++) {
          int d = cc * 8 + j;
          int byt = (d * 72 + row) * 2;
          byt ^= ((d >> 3) & 7) << 4;  // spread transpose-writes across banks
          *(unsigned short*)((char*)V_lds + byt) = (unsigned short)vv[j];
        }
      }
    }
    __syncthreads();

    // S = Q K^T : A=Q (row=l15), B=K^T read from row-major K (col=l15)
    f32x4 sacc[4];
#pragma unroll
    for (int kn = 0; kn < 4; kn++) sacc[kn] = (f32x4){0.f, 0.f, 0.f, 0.f};
#pragma unroll
    for (int kn = 0; kn < 4; kn++)
#pragma unroll
      for (int kc = 0; kc < 2; kc++) {
        bf16x8 bk = *(const bf16x8*)(&K_lds[(kn * 16 + l15) * 72 + kc * 32 + lg * 8]);
        sacc[kn] = __builtin_amdgcn_mfma_f32_16x16x32_bf16(aq[kc], bk, sacc[kn], 0, 0, 0);
      }

    // scale 1/sqrt(64) then multiplicative mask (pre-softmax, per reference)
    float sv[4][4];
#pragma unroll
    for (int kn = 0; kn < 4; kn++)
#pragma unroll
      for (int r = 0; r < 4; r++) {
        float mk = bf2f(mb[(size_t)(qrow + r) * S_ + kt * 64 + kn * 16 + l15]);
        sv[kn][r] = sacc[kn][r] * 0.125f * mk;
      }

    // online softmax per q-row (row spread over 16 lanes of the group)
#pragma unroll
    for (int r = 0; r < 4; r++) {
      float tmax = fmaxf(fmaxf(sv[0][r], sv[1][r]), fmaxf(sv[2][r], sv[3][r]));
#pragma unroll
      for (int off = 1; off < 16; off <<= 1) tmax = fmaxf(tmax, __shfl_xor(tmax, off));
      float mn = fmaxf(m_r[r], tmax);
      float alpha = exp2f((m_r[r] - mn) * 1.44269504f);
      m_r[r] = mn;
      l_r[r] *= alpha;
#pragma unroll
      for (int dn = 0; dn < 4; dn++) o_acc[dn][r] *= alpha;
      float rs = 0.f;
#pragma unroll
      for (int kn = 0; kn < 4; kn++) {
        float p = exp2f((sv[kn][r] - mn) * 1.44269504f);
        sv[kn][r] = p;
        rs += p;
      }
#pragma unroll
      for (int off = 1; off < 16; off <<= 1) rs += __shfl_xor(rs, off);
      l_r[r] += rs;
    }

    // P (C-layout) -> LDS -> A-layout fragments, bf16
#pragma unroll
    for (int kn = 0; kn < 4; kn++)
#pragma unroll
      for (int r = 0; r < 4; r++)
        pw[(lg * 4 + r) * 72 + kn * 16 + l15] = f2bf(sv[kn][r]);

    // O += P V : A=P (row=l15), B=V (col=l15 via transposed V_lds)
#pragma unroll
    for (int kc = 0; kc < 2; kc++) {
      bf16x8 ap = *(const bf16x8*)(&pw[l15 * 72 + kc * 32 + lg * 8]);
#pragma unroll
      for (int dn = 0; dn < 4; dn++) {
        int dc = dn * 16 + l15;
        int byt = (dc * 72 + kc * 32 + lg * 8) * 2;
        byt ^= ((dc >> 3) & 7) << 4;
        bf16x8 bv = *(const bf16x8*)((char*)V_lds + byt);
        o_acc[dn] = __builtin_amdgcn_mfma_f32_16x16x32_bf16(ap, bv, o_acc[dn], 0, 0, 0);
      }
    }
  }

#pragma unroll
  for (int dn = 0; dn < 4; dn++)
#pragma unroll
    for (int r = 0; r < 4; r++)
      out[(size_t)(b * S_ + qrow + r) * D_ + h * DH_ + dn * 16 + l15] = o_acc[dn][r] / l_r[r];
}

// ---------------- host launch ----------------
extern "C" void kernel_launch(void* const* d_in, const int* in_sizes, int n_in,
                              void* d_out, int out_size, void* d_ws, size_t ws_size,
                              hipStream_t stream) {
  const float* q = (const float*)d_in[0];
  const float* k = (const float*)d_in[1];
  const float* v = (const float*)d_in[2];
  const float* mask = (const float*)d_in[3];
  const float* Wq = (const float*)d_in[4];
  const float* Wk = (const float*)d_in[5];
  const float* Wv = (const float*)d_in[6];

  // ws layout (bytes): qh 16.78M | kh 16.78M | vh 16.78M | mask_bf16 8.39M | Wt 6.29M = 62MB
  char* ws = (char*)d_ws;
  const size_t SZ_PROJ = (size_t)B_ * S_ * D_ * 2;  // 16,777,216
  unsigned short* qh = (unsigned short*)(ws);
  unsigned short* kh = (unsigned short*)(ws + SZ_PROJ);
  unsigned short* vh = (unsigned short*)(ws + 2 * SZ_PROJ);
  unsigned short* mb = (unsigned short*)(ws + 3 * SZ_PROJ);
  unsigned short* Wt = (unsigned short*)(ws + 3 * SZ_PROJ + (size_t)S_ * S_ * 2);

  mconv_kernel<<<4096, 256, 0, stream>>>(mask, mb);
  wtrans_kernel<<<dim3(D_ / 32, D_ / 32, 3), dim3(32, 8), 0, stream>>>(Wq, Wk, Wv, Wt);
  proj_kernel<<<dim3(D_ / 128, (B_ * S_) / 128, 3), 256, 0, stream>>>(q, k, v, Wt, qh);
  attn_kernel<<<dim3(S_ / 64, H_, B_), 256, 0, stream>>>(qh, kh, vh, mb, (float*)d_out);
}

// Round 3
// 344.303 us; speedup vs baseline: 1.2453x; 1.2453x over previous
//
#include <hip/hip_runtime.h>

#define B_  4
#define S_  2048
#define D_  1024
#define H_  16
#define DH_ 64

typedef __attribute__((ext_vector_type(8))) short bf16x8;
typedef __attribute__((ext_vector_type(4))) float f32x4;
typedef __attribute__((ext_vector_type(4))) unsigned short u16x4;

__device__ __forceinline__ unsigned short f2bf(float f) {
  union { float f; unsigned int u; } x; x.f = f;
  unsigned int u = x.u;
  unsigned int r = (u + 0x7fffu + ((u >> 16) & 1u)) >> 16;  // RNE
  return (unsigned short)r;
}

__device__ __forceinline__ int cvtpk(float lo, float hi) {
  unsigned r;
  asm("v_cvt_pk_bf16_f32 %0, %1, %2" : "=v"(r) : "v"(lo), "v"(hi));
  return (int)r;
}
__device__ __forceinline__ float bperm_f(int addr, float v) {
  union { float f; int i; } x; x.f = v;
  x.i = __builtin_amdgcn_ds_bpermute(addr, x.i);
  return x.f;
}

// ---------------- W (fp32 [k][n]) -> Wt (bf16 [n][k]) ----------------
__global__ __launch_bounds__(256) void wtrans_kernel(const float* __restrict__ W0,
                                                     const float* __restrict__ W1,
                                                     const float* __restrict__ W2,
                                                     unsigned short* __restrict__ Wt) {
  __shared__ float t[32][33];
  const int z = blockIdx.z;
  const float* W = (z == 0) ? W0 : ((z == 1) ? W1 : W2);
  unsigned short* O = Wt + (size_t)z * (D_ * D_);
  const int n0 = blockIdx.x * 32, k0 = blockIdx.y * 32;
  const int tx = threadIdx.x, ty = threadIdx.y;
#pragma unroll
  for (int i = 0; i < 4; i++) t[ty + i * 8][tx] = W[(size_t)(k0 + ty + i * 8) * D_ + n0 + tx];
  __syncthreads();
#pragma unroll
  for (int i = 0; i < 4; i++)
    O[(size_t)(n0 + ty + i * 8) * D_ + k0 + tx] = f2bf(t[tx][ty + i * 8]);
}

// ---------------- projection GEMM: Y(bf16) = X(fp32) @ W, via Wt ----------------
__global__ __launch_bounds__(256) void proj_kernel(const float* __restrict__ X0,
                                                   const float* __restrict__ X1,
                                                   const float* __restrict__ X2,
                                                   const unsigned short* __restrict__ Wt,
                                                   unsigned short* __restrict__ Y0) {
  __shared__ unsigned short Alds[128 * 72];
  __shared__ unsigned short Blds[128 * 72];
  const int z = blockIdx.z;
  const float* X = (z == 0) ? X0 : ((z == 1) ? X1 : X2);
  const unsigned short* Wz = Wt + (size_t)z * (D_ * D_);
  unsigned short* Y = Y0 + (size_t)z * ((size_t)B_ * S_ * D_);

  const int tid = threadIdx.x;
  const int lane = tid & 63, w = tid >> 6;
  const int wr = w >> 1, wc = w & 1;
  const int l15 = lane & 15, lg = lane >> 4;
  const int r0 = blockIdx.y * 128, c0 = blockIdx.x * 128;

  f32x4 acc[4][4];
#pragma unroll
  for (int m = 0; m < 4; m++)
#pragma unroll
    for (int n = 0; n < 4; n++) acc[m][n] = (f32x4){0.f, 0.f, 0.f, 0.f};

  for (int kt = 0; kt < 16; ++kt) {
    __syncthreads();
    {
      const int rr = tid >> 4, cf = (tid & 15) * 4;
#pragma unroll
      for (int p = 0; p < 8; p++) {
        int row = rr + p * 16;
        float4 xv = *(const float4*)(X + (size_t)(r0 + row) * D_ + kt * 64 + cf);
        u16x4 bb = { f2bf(xv.x), f2bf(xv.y), f2bf(xv.z), f2bf(xv.w) };
        *(u16x4*)(&Alds[row * 72 + cf]) = bb;
      }
      const int rb = tid >> 3, cb = tid & 7;
#pragma unroll
      for (int p = 0; p < 4; p++) {
        int row = rb + p * 32;
        bf16x8 wv = *(const bf16x8*)(Wz + (size_t)(c0 + row) * D_ + kt * 64 + cb * 8);
        *(bf16x8*)(&Blds[row * 72 + cb * 8]) = wv;
      }
    }
    __syncthreads();

    bf16x8 af[4][2];
#pragma unroll
    for (int m = 0; m < 4; m++)
#pragma unroll
      for (int kc = 0; kc < 2; kc++)
        af[m][kc] = *(const bf16x8*)(&Alds[(wr * 64 + m * 16 + l15) * 72 + kc * 32 + lg * 8]);
#pragma unroll
    for (int n = 0; n < 4; n++) {
      bf16x8 bfr[2];
#pragma unroll
      for (int kc = 0; kc < 2; kc++)
        bfr[kc] = *(const bf16x8*)(&Blds[(wc * 64 + n * 16 + l15) * 72 + kc * 32 + lg * 8]);
#pragma unroll
      for (int m = 0; m < 4; m++)
#pragma unroll
        for (int kc = 0; kc < 2; kc++)
          acc[m][n] = __builtin_amdgcn_mfma_f32_16x16x32_bf16(af[m][kc], bfr[kc], acc[m][n], 0, 0, 0);
    }
  }

#pragma unroll
  for (int m = 0; m < 4; m++)
#pragma unroll
    for (int n = 0; n < 4; n++)
#pragma unroll
      for (int r = 0; r < 4; r++) {
        int row = r0 + wr * 64 + m * 16 + lg * 4 + r;
        int col = c0 + wc * 64 + n * 16 + l15;
        Y[(size_t)row * D_ + col] = f2bf(acc[m][n][r]);
      }
}

// ---------------- fused attention (swapped QK^T, in-register softmax) ----------------
// grid (S/64, H, B); 4 waves; wave w owns q-rows [q0+16w, q0+16w+16)
// K_lds: row-major [64][72] shorts (round-1 layout). V_lds: transposed [d][k],
// 72-pitch, byte-XOR swizzle ((d>>3)&7)<<4 (round-1 layout). Double-buffered,
// one barrier per tile; next-tile global loads issued before the barrier (T14).
__global__ __launch_bounds__(256) void attn_kernel(
    const unsigned short* __restrict__ qh,
    const unsigned short* __restrict__ kh,
    const unsigned short* __restrict__ vh,
    const float* __restrict__ mask,
    float* __restrict__ out) {
  __shared__ __align__(16) unsigned short K_lds[2][64 * 72];
  __shared__ __align__(16) unsigned short V_lds[2][64 * 72];

  const int tid = threadIdx.x;
  const int lane = tid & 63, w = tid >> 6;
  const int l15 = lane & 15, lg = lane >> 4;
  const int q0 = blockIdx.x * 64;
  const int h = blockIdx.y, b = blockIdx.z;
  const size_t head = (size_t)b * S_ * D_ + h * DH_;

  // Q as B-fragments (resident): B[d][q], q = l15, d = kc*32 + lg*8 + j
  bf16x8 bq[2];
  {
    const unsigned short* qp = qh + head + (size_t)(q0 + w * 16 + l15) * D_;
#pragma unroll
    for (int kc = 0; kc < 2; kc++) bq[kc] = *(const bf16x8*)(qp + kc * 32 + lg * 8);
  }

  // staging geometry (round-1): thread handles rows rr, rr+32; 16B at col cc*8
  const int rr = tid >> 3, cc = tid & 7;
  const unsigned short* kbase = kh + head + (size_t)rr * D_ + cc * 8;
  const unsigned short* vbase = vh + head + (size_t)rr * D_ + cc * 8;

  // cross-lane addresses
  const int aL0 = (((lg & 1) * 32 + l15) << 2);  // src lanes for dest words t=0,1
  const int aL1 = aL0 + 64;                      // t=2,3 (+16 lanes)
  const int selhi = lg >> 1;
  int badr[4];
#pragma unroll
  for (int r = 0; r < 4; r++) badr[r] = (lg * 16 + lg * 4 + r) << 2;  // lane with l15 == lg*4+r

  f32x4 o_acc[4];
#pragma unroll
  for (int dn = 0; dn < 4; dn++) o_acc[dn] = (f32x4){0.f, 0.f, 0.f, 0.f};
  float m_r = -INFINITY, l_r = 0.f;

  // preload tile 0 and write buffer 0
  bf16x8 kreg[2], vreg[2];
#pragma unroll
  for (int p = 0; p < 2; p++) {
    kreg[p] = *(const bf16x8*)(kbase + (size_t)p * 32 * D_);
    vreg[p] = *(const bf16x8*)(vbase + (size_t)p * 32 * D_);
  }
#pragma unroll
  for (int p = 0; p < 2; p++) {
    int row = rr + p * 32;
    *(bf16x8*)(&K_lds[0][row * 72 + cc * 8]) = kreg[p];
#pragma unroll
    for (int j = 0; j < 8; j++) {
      int d = cc * 8 + j;
      int byt = (d * 72 + row) * 2;
      byt ^= ((d >> 3) & 7) << 4;
      *(unsigned short*)((char*)&V_lds[0][0] + byt) = (unsigned short)vreg[p][j];
    }
  }

  const float cs = 0.125f * 1.44269504f;  // 1/sqrt(DH) * log2(e)

  for (int kt = 0; kt < 32; kt++) {
    const int cur = kt & 1;

    // issue next tile's global loads early (latency hides under compute)
    bf16x8 kreg2[2], vreg2[2];
    if (kt + 1 < 32) {
      const size_t tb = (size_t)(kt + 1) * 64 * D_;
#pragma unroll
      for (int p = 0; p < 2; p++) {
        kreg2[p] = *(const bf16x8*)(kbase + tb + (size_t)p * 32 * D_);
        vreg2[p] = *(const bf16x8*)(vbase + tb + (size_t)p * 32 * D_);
      }
    }

    __syncthreads();  // buf[cur] fully written; everyone done reading buf[cur^1]

    // S^T = K · Q^T : lane holds S^T[k = kn*16 + lg*4 + r][q = l15]
    f32x4 sacc[4];
#pragma unroll
    for (int kn = 0; kn < 4; kn++) sacc[kn] = (f32x4){0.f, 0.f, 0.f, 0.f};
#pragma unroll
    for (int kc = 0; kc < 2; kc++)
#pragma unroll
      for (int kn = 0; kn < 4; kn++) {
        bf16x8 ak = *(const bf16x8*)(&K_lds[cur][(kn * 16 + l15) * 72 + kc * 32 + lg * 8]);
        sacc[kn] = __builtin_amdgcn_mfma_f32_16x16x32_bf16(ak, bq[kc], sacc[kn], 0, 0, 0);
      }

    // scale * mask (fp32, per-lane float4), into log2 domain
    float sl[16];
    const float* mrow = mask + (size_t)(q0 + w * 16 + l15) * S_ + kt * 64 + lg * 4;
#pragma unroll
    for (int kn = 0; kn < 4; kn++) {
      float4 mk = *(const float4*)(mrow + kn * 16);
      sl[kn * 4 + 0] = sacc[kn][0] * (cs * mk.x);
      sl[kn * 4 + 1] = sacc[kn][1] * (cs * mk.y);
      sl[kn * 4 + 2] = sacc[kn][2] * (cs * mk.z);
      sl[kn * 4 + 3] = sacc[kn][3] * (cs * mk.w);
    }

    // online softmax: in-lane 15 + 2 shfl (lanes with same l15 hold same q-row)
    float tm = sl[0];
#pragma unroll
    for (int i = 1; i < 16; i++) tm = fmaxf(tm, sl[i]);
    tm = fmaxf(tm, __shfl_xor(tm, 16));
    tm = fmaxf(tm, __shfl_xor(tm, 32));

    float mn;
    if (__any(tm > m_r + 8.0f)) {  // defer-max (THR=8 in log2 domain)
      mn = fmaxf(m_r, tm);
      float alpha = exp2f(m_r - mn);
      m_r = mn;
      l_r *= alpha;
#pragma unroll
      for (int r = 0; r < 4; r++) {
        float ao = bperm_f(badr[r], alpha);  // alpha indexed by q=l15 -> rows lg*4+r
#pragma unroll
        for (int dn = 0; dn < 4; dn++) o_acc[dn][r] *= ao;
      }
    } else {
      mn = m_r;
    }

    float rs = 0.f;
#pragma unroll
    for (int i = 0; i < 16; i++) {
      float p = exp2f(sl[i] - mn);
      sl[i] = p;
      rs += p;
    }
    rs += __shfl_xor(rs, 16);
    rs += __shfl_xor(rs, 32);
    l_r += rs;

    // P: C-layout -> bf16 words; permute BOTH kn' candidates, select by dest lg>>1.
    // src lane holds pw[kn*2+h] = P[q=l15][k = kn*16 + lg*4 + 2h (lo), +1 (hi)]
    int pw[8];
#pragma unroll
    for (int kn = 0; kn < 4; kn++) {
      pw[kn * 2 + 0] = cvtpk(sl[kn * 4 + 0], sl[kn * 4 + 1]);
      pw[kn * 2 + 1] = cvtpk(sl[kn * 4 + 2], sl[kn * 4 + 3]);
    }
    bf16x8 af[2];
#pragma unroll
    for (int kc = 0; kc < 2; kc++) {
      int pA0 = pw[(kc * 2 + 0) * 2 + 0], pA1 = pw[(kc * 2 + 0) * 2 + 1];
      int pB0 = pw[(kc * 2 + 1) * 2 + 0], pB1 = pw[(kc * 2 + 1) * 2 + 1];
      int a0 = __builtin_amdgcn_ds_bpermute(aL0, pA0);
      int b0 = __builtin_amdgcn_ds_bpermute(aL0, pB0);
      int a1 = __builtin_amdgcn_ds_bpermute(aL0, pA1);
      int b1 = __builtin_amdgcn_ds_bpermute(aL0, pB1);
      int a2 = __builtin_amdgcn_ds_bpermute(aL1, pA0);
      int b2 = __builtin_amdgcn_ds_bpermute(aL1, pB0);
      int a3 = __builtin_amdgcn_ds_bpermute(aL1, pA1);
      int b3 = __builtin_amdgcn_ds_bpermute(aL1, pB1);
      union { int u[4]; bf16x8 v; } cv;
      cv.u[0] = selhi ? b0 : a0;
      cv.u[1] = selhi ? b1 : a1;
      cv.u[2] = selhi ? b2 : a2;
      cv.u[3] = selhi ? b3 : a3;
      af[kc] = cv.v;
    }

    // O += P·V : B-fragment from transposed+swizzled V_lds (round-1 path)
#pragma unroll
    for (int kc = 0; kc < 2; kc++)
#pragma unroll
      for (int dn = 0; dn < 4; dn++) {
        int dc = dn * 16 + l15;
        int byt = (dc * 72 + kc * 32 + lg * 8) * 2;
        byt ^= ((dc >> 3) & 7) << 4;
        bf16x8 bv = *(const bf16x8*)((const char*)&V_lds[cur][0] + byt);
        o_acc[dn] = __builtin_amdgcn_mfma_f32_16x16x32_bf16(af[kc], bv, o_acc[dn], 0, 0, 0);
      }

    // write next tile into the other buffer (safe: all waves past the barrier)
    if (kt + 1 < 32) {
#pragma unroll
      for (int p = 0; p < 2; p++) {
        int row = rr + p * 32;
        *(bf16x8*)(&K_lds[cur ^ 1][row * 72 + cc * 8]) = kreg2[p];
#pragma unroll
        for (int j = 0; j < 8; j++) {
          int d = cc * 8 + j;
          int byt = (d * 72 + row) * 2;
          byt ^= ((d >> 3) & 7) << 4;
          *(unsigned short*)((char*)&V_lds[cur ^ 1][0] + byt) = (unsigned short)vreg2[p][j];
        }
      }
    }
  }

  // epilogue: O / l  (l indexed by q=l15 -> move to C rows lg*4+r)
  float inv[4];
#pragma unroll
  for (int r = 0; r < 4; r++) inv[r] = 1.0f / bperm_f(badr[r], l_r);
  float* op = out + (size_t)(b * S_ + q0 + w * 16) * D_ + h * DH_;
#pragma unroll
  for (int dn = 0; dn < 4; dn++)
#pragma unroll
    for (int r = 0; r < 4; r++)
      op[(size_t)(lg * 4 + r) * D_ + dn * 16 + l15] = o_acc[dn][r] * inv[r];
}

// ---------------- host launch ----------------
extern "C" void kernel_launch(void* const* d_in, const int* in_sizes, int n_in,
                              void* d_out, int out_size, void* d_ws, size_t ws_size,
                              hipStream_t stream) {
  const float* q = (const float*)d_in[0];
  const float* k = (const float*)d_in[1];
  const float* v = (const float*)d_in[2];
  const float* mask = (const float*)d_in[3];
  const float* Wq = (const float*)d_in[4];
  const float* Wk = (const float*)d_in[5];
  const float* Wv = (const float*)d_in[6];

  // ws: qh 16.78M | kh 16.78M | vh 16.78M | Wt 6.29M
  char* ws = (char*)d_ws;
  const size_t SZ_PROJ = (size_t)B_ * S_ * D_ * 2;
  unsigned short* qh = (unsigned short*)(ws);
  unsigned short* kh = (unsigned short*)(ws + SZ_PROJ);
  unsigned short* vh = (unsigned short*)(ws + 2 * SZ_PROJ);
  unsigned short* Wt = (unsigned short*)(ws + 3 * SZ_PROJ);

  wtrans_kernel<<<dim3(D_ / 32, D_ / 32, 3), dim3(32, 8), 0, stream>>>(Wq, Wk, Wv, Wt);
  proj_kernel<<<dim3(D_ / 128, (B_ * S_) / 128, 3), 256, 0, stream>>>(q, k, v, Wt, qh);
  attn_kernel<<<dim3(S_ / 64, H_, B_), 256, 0, stream>>>(qh, kh, vh, mask, (float*)d_out);
}

// Round 5
// 323.380 us; speedup vs baseline: 1.3259x; 1.0647x over previous
//
#include <hip/hip_runtime.h>

#define B_  4
#define S_  2048
#define D_  1024
#define H_  16
#define DH_ 64

typedef __attribute__((ext_vector_type(8))) short bf16x8;
typedef __attribute__((ext_vector_type(4))) float f32x4;
typedef __attribute__((ext_vector_type(4))) unsigned short u16x4;

__device__ __forceinline__ unsigned short f2bf(float f) {
  union { float f; unsigned int u; } x; x.f = f;
  unsigned int u = x.u;
  unsigned int r = (u + 0x7fffu + ((u >> 16) & 1u)) >> 16;  // RNE
  return (unsigned short)r;
}

__device__ __forceinline__ int cvtpk(float lo, float hi) {
  unsigned r;
  asm("v_cvt_pk_bf16_f32 %0, %1, %2" : "=v"(r) : "v"(lo), "v"(hi));
  return (int)r;
}
__device__ __forceinline__ float bperm_f(int addr, float v) {
  union { float f; int i; } x; x.f = v;
  x.i = __builtin_amdgcn_ds_bpermute(addr, x.i);
  return x.f;
}

// ---------------- W (fp32 [k][n]) -> Wt (bf16 [n][k]) ----------------
__global__ __launch_bounds__(256) void wtrans_kernel(const float* __restrict__ W0,
                                                     const float* __restrict__ W1,
                                                     const float* __restrict__ W2,
                                                     unsigned short* __restrict__ Wt) {
  __shared__ float t[32][33];
  const int z = blockIdx.z;
  const float* W = (z == 0) ? W0 : ((z == 1) ? W1 : W2);
  unsigned short* O = Wt + (size_t)z * (D_ * D_);
  const int n0 = blockIdx.x * 32, k0 = blockIdx.y * 32;
  const int tx = threadIdx.x, ty = threadIdx.y;
#pragma unroll
  for (int i = 0; i < 4; i++) t[ty + i * 8][tx] = W[(size_t)(k0 + ty + i * 8) * D_ + n0 + tx];
  __syncthreads();
#pragma unroll
  for (int i = 0; i < 4; i++)
    O[(size_t)(n0 + ty + i * 8) * D_ + k0 + tx] = f2bf(t[tx][ty + i * 8]);
}

// ---------------- projection GEMM: Y(bf16) = X(fp32) @ W, via Wt ----------------
__global__ __launch_bounds__(256) void proj_kernel(const float* __restrict__ X0,
                                                   const float* __restrict__ X1,
                                                   const float* __restrict__ X2,
                                                   const unsigned short* __restrict__ Wt,
                                                   unsigned short* __restrict__ Y0) {
  __shared__ unsigned short Alds[128 * 72];
  __shared__ unsigned short Blds[128 * 72];
  const int z = blockIdx.z;
  const float* X = (z == 0) ? X0 : ((z == 1) ? X1 : X2);
  const unsigned short* Wz = Wt + (size_t)z * (D_ * D_);
  unsigned short* Y = Y0 + (size_t)z * ((size_t)B_ * S_ * D_);

  const int tid = threadIdx.x;
  const int lane = tid & 63, w = tid >> 6;
  const int wr = w >> 1, wc = w & 1;
  const int l15 = lane & 15, lg = lane >> 4;
  const int r0 = blockIdx.y * 128, c0 = blockIdx.x * 128;

  f32x4 acc[4][4];
#pragma unroll
  for (int m = 0; m < 4; m++)
#pragma unroll
    for (int n = 0; n < 4; n++) acc[m][n] = (f32x4){0.f, 0.f, 0.f, 0.f};

  for (int kt = 0; kt < 16; ++kt) {
    __syncthreads();
    {
      const int rr = tid >> 4, cf = (tid & 15) * 4;
#pragma unroll
      for (int p = 0; p < 8; p++) {
        int row = rr + p * 16;
        float4 xv = *(const float4*)(X + (size_t)(r0 + row) * D_ + kt * 64 + cf);
        u16x4 bb = { f2bf(xv.x), f2bf(xv.y), f2bf(xv.z), f2bf(xv.w) };
        *(u16x4*)(&Alds[row * 72 + cf]) = bb;
      }
      const int rb = tid >> 3, cb = tid & 7;
#pragma unroll
      for (int p = 0; p < 4; p++) {
        int row = rb + p * 32;
        bf16x8 wv = *(const bf16x8*)(Wz + (size_t)(c0 + row) * D_ + kt * 64 + cb * 8);
        *(bf16x8*)(&Blds[row * 72 + cb * 8]) = wv;
      }
    }
    __syncthreads();

    bf16x8 af[4][2];
#pragma unroll
    for (int m = 0; m < 4; m++)
#pragma unroll
      for (int kc = 0; kc < 2; kc++)
        af[m][kc] = *(const bf16x8*)(&Alds[(wr * 64 + m * 16 + l15) * 72 + kc * 32 + lg * 8]);
#pragma unroll
    for (int n = 0; n < 4; n++) {
      bf16x8 bfr[2];
#pragma unroll
      for (int kc = 0; kc < 2; kc++)
        bfr[kc] = *(const bf16x8*)(&Blds[(wc * 64 + n * 16 + l15) * 72 + kc * 32 + lg * 8]);
#pragma unroll
      for (int m = 0; m < 4; m++)
#pragma unroll
        for (int kc = 0; kc < 2; kc++)
          acc[m][n] = __builtin_amdgcn_mfma_f32_16x16x32_bf16(af[m][kc], bfr[kc], acc[m][n], 0, 0, 0);
    }
  }

#pragma unroll
  for (int m = 0; m < 4; m++)
#pragma unroll
    for (int n = 0; n < 4; n++)
#pragma unroll
      for (int r = 0; r < 4; r++) {
        int row = r0 + wr * 64 + m * 16 + lg * 4 + r;
        int col = c0 + wc * 64 + n * 16 + l15;
        Y[(size_t)row * D_ + col] = f2bf(acc[m][n][r]);
      }
}

// ---------------- fused attention (swapped QK^T, 2 q-groups per wave) ----------------
// grid (S/128, H, B); 4 waves; wave w owns q-rows [q0+32w, q0+32w+32), split into
// groups g=0,1 of 16. K/V fragment reads are q-independent -> reused across groups.
// K_lds row-major [64][72], V_lds transposed [d][k] 72-pitch XOR-swizzled
// (round-1/3 verified layouts). Double-buffered, 1 barrier/tile, early prefetch.
__global__ __launch_bounds__(256) void attn_kernel(
    const unsigned short* __restrict__ qh,
    const unsigned short* __restrict__ kh,
    const unsigned short* __restrict__ vh,
    const float* __restrict__ mask,
    float* __restrict__ out) {
  __shared__ __align__(16) unsigned short K_lds[2][64 * 72];
  __shared__ __align__(16) unsigned short V_lds[2][64 * 72];

  const int tid = threadIdx.x;
  const int lane = tid & 63, w = tid >> 6;
  const int l15 = lane & 15, lg = lane >> 4;
  const int q0 = blockIdx.x * 128;
  const int h = blockIdx.y, b = blockIdx.z;
  const size_t head = (size_t)b * S_ * D_ + h * DH_;

  // Q as B-fragments (resident), one per group: B[d][q], q = l15
  bf16x8 bq[2][2];
#pragma unroll
  for (int g = 0; g < 2; g++) {
    const unsigned short* qp = qh + head + (size_t)(q0 + w * 32 + g * 16 + l15) * D_;
#pragma unroll
    for (int kc = 0; kc < 2; kc++) bq[g][kc] = *(const bf16x8*)(qp + kc * 32 + lg * 8);
  }

  // staging geometry (verified r3): thread handles rows rr, rr+32; 16B at col cc*8
  const int rr = tid >> 3, cc = tid & 7;
  const unsigned short* kbase = kh + head + (size_t)rr * D_ + cc * 8;
  const unsigned short* vbase = vh + head + (size_t)rr * D_ + cc * 8;

  // cross-lane addresses (verified r3)
  const int aL0 = (((lg & 1) * 32 + l15) << 2);
  const int aL1 = aL0 + 64;
  const int selhi = lg >> 1;
  int badr[4];
#pragma unroll
  for (int r = 0; r < 4; r++) badr[r] = (lg * 16 + lg * 4 + r) << 2;

  f32x4 o_acc[2][4];
#pragma unroll
  for (int g = 0; g < 2; g++)
#pragma unroll
    for (int dn = 0; dn < 4; dn++) o_acc[g][dn] = (f32x4){0.f, 0.f, 0.f, 0.f};
  float m_r[2] = {-INFINITY, -INFINITY}, l_r[2] = {0.f, 0.f};

  // preload tile 0 and write buffer 0
  bf16x8 kreg[2], vreg[2];
#pragma unroll
  for (int p = 0; p < 2; p++) {
    kreg[p] = *(const bf16x8*)(kbase + (size_t)p * 32 * D_);
    vreg[p] = *(const bf16x8*)(vbase + (size_t)p * 32 * D_);
  }
#pragma unroll
  for (int p = 0; p < 2; p++) {
    int row = rr + p * 32;
    *(bf16x8*)(&K_lds[0][row * 72 + cc * 8]) = kreg[p];
#pragma unroll
    for (int j = 0; j < 8; j++) {
      int d = cc * 8 + j;
      int byt = (d * 72 + row) * 2;
      byt ^= ((d >> 3) & 7) << 4;
      *(unsigned short*)((char*)&V_lds[0][0] + byt) = (unsigned short)vreg[p][j];
    }
  }

  const float cs = 0.125f * 1.44269504f;  // 1/sqrt(DH) * log2(e)

  for (int kt = 0; kt < 32; kt++) {
    const int cur = kt & 1;

    // issue next tile's global loads early (latency hides under compute)
    bf16x8 kreg2[2], vreg2[2];
    if (kt + 1 < 32) {
      const size_t tb = (size_t)(kt + 1) * 64 * D_;
#pragma unroll
      for (int p = 0; p < 2; p++) {
        kreg2[p] = *(const bf16x8*)(kbase + tb + (size_t)p * 32 * D_);
        vreg2[p] = *(const bf16x8*)(vbase + tb + (size_t)p * 32 * D_);
      }
    }

    __syncthreads();  // buf[cur] fully written; everyone done reading buf[cur^1]

    // S^T = K · Q^T for both groups; K fragment loaded ONCE, used twice
    f32x4 sacc[2][4];
#pragma unroll
    for (int g = 0; g < 2; g++)
#pragma unroll
      for (int kn = 0; kn < 4; kn++) sacc[g][kn] = (f32x4){0.f, 0.f, 0.f, 0.f};
#pragma unroll
    for (int kc = 0; kc < 2; kc++)
#pragma unroll
      for (int kn = 0; kn < 4; kn++) {
        bf16x8 ak = *(const bf16x8*)(&K_lds[cur][(kn * 16 + l15) * 72 + kc * 32 + lg * 8]);
        sacc[0][kn] = __builtin_amdgcn_mfma_f32_16x16x32_bf16(ak, bq[0][kc], sacc[0][kn], 0, 0, 0);
        sacc[1][kn] = __builtin_amdgcn_mfma_f32_16x16x32_bf16(ak, bq[1][kc], sacc[1][kn], 0, 0, 0);
      }

    // per-group: mask/scale, online softmax, P -> A-fragments
    bf16x8 af[2][2];
#pragma unroll
    for (int g = 0; g < 2; g++) {
      float sl[16];
      const float* mrow = mask + (size_t)(q0 + w * 32 + g * 16 + l15) * S_ + kt * 64 + lg * 4;
#pragma unroll
      for (int kn = 0; kn < 4; kn++) {
        float4 mk = *(const float4*)(mrow + kn * 16);
        sl[kn * 4 + 0] = sacc[g][kn][0] * (cs * mk.x);
        sl[kn * 4 + 1] = sacc[g][kn][1] * (cs * mk.y);
        sl[kn * 4 + 2] = sacc[g][kn][2] * (cs * mk.z);
        sl[kn * 4 + 3] = sacc[g][kn][3] * (cs * mk.w);
      }

      float tm = sl[0];
#pragma unroll
      for (int i = 1; i < 16; i++) tm = fmaxf(tm, sl[i]);
      tm = fmaxf(tm, __shfl_xor(tm, 16));
      tm = fmaxf(tm, __shfl_xor(tm, 32));

      float mn;
      if (__any(tm > m_r[g] + 8.0f)) {  // defer-max (THR=8 in log2 domain)
        mn = fmaxf(m_r[g], tm);
        float alpha = exp2f(m_r[g] - mn);
        m_r[g] = mn;
        l_r[g] *= alpha;
#pragma unroll
        for (int r = 0; r < 4; r++) {
          float ao = bperm_f(badr[r], alpha);
#pragma unroll
          for (int dn = 0; dn < 4; dn++) o_acc[g][dn][r] *= ao;
        }
      } else {
        mn = m_r[g];
      }

      float rs = 0.f;
#pragma unroll
      for (int i = 0; i < 16; i++) {
        float p = exp2f(sl[i] - mn);
        sl[i] = p;
        rs += p;
      }
      rs += __shfl_xor(rs, 16);
      rs += __shfl_xor(rs, 32);
      l_r[g] += rs;

      // P: C-layout -> bf16 words; permute both candidates, select by dest lg>>1
      int pw[8];
#pragma unroll
      for (int kn = 0; kn < 4; kn++) {
        pw[kn * 2 + 0] = cvtpk(sl[kn * 4 + 0], sl[kn * 4 + 1]);
        pw[kn * 2 + 1] = cvtpk(sl[kn * 4 + 2], sl[kn * 4 + 3]);
      }
#pragma unroll
      for (int kc = 0; kc < 2; kc++) {
        int pA0 = pw[(kc * 2 + 0) * 2 + 0], pA1 = pw[(kc * 2 + 0) * 2 + 1];
        int pB0 = pw[(kc * 2 + 1) * 2 + 0], pB1 = pw[(kc * 2 + 1) * 2 + 1];
        int a0 = __builtin_amdgcn_ds_bpermute(aL0, pA0);
        int b0 = __builtin_amdgcn_ds_bpermute(aL0, pB0);
        int a1 = __builtin_amdgcn_ds_bpermute(aL0, pA1);
        int b1 = __builtin_amdgcn_ds_bpermute(aL0, pB1);
        int a2 = __builtin_amdgcn_ds_bpermute(aL1, pA0);
        int b2 = __builtin_amdgcn_ds_bpermute(aL1, pB0);
        int a3 = __builtin_amdgcn_ds_bpermute(aL1, pA1);
        int b3 = __builtin_amdgcn_ds_bpermute(aL1, pB1);
        union { int u[4]; bf16x8 v; } cv;
        cv.u[0] = selhi ? b0 : a0;
        cv.u[1] = selhi ? b1 : a1;
        cv.u[2] = selhi ? b2 : a2;
        cv.u[3] = selhi ? b3 : a3;
        af[g][kc] = cv.v;
      }
    }

    // O += P·V for both groups; V fragment loaded ONCE, used twice
#pragma unroll
    for (int kc = 0; kc < 2; kc++)
#pragma unroll
      for (int dn = 0; dn < 4; dn++) {
        int dc = dn * 16 + l15;
        int byt = (dc * 72 + kc * 32 + lg * 8) * 2;
        byt ^= ((dc >> 3) & 7) << 4;
        bf16x8 bv = *(const bf16x8*)((const char*)&V_lds[cur][0] + byt);
        o_acc[0][dn] = __builtin_amdgcn_mfma_f32_16x16x32_bf16(af[0][kc], bv, o_acc[0][dn], 0, 0, 0);
        o_acc[1][dn] = __builtin_amdgcn_mfma_f32_16x16x32_bf16(af[1][kc], bv, o_acc[1][dn], 0, 0, 0);
      }

    // write next tile into the other buffer
    if (kt + 1 < 32) {
#pragma unroll
      for (int p = 0; p < 2; p++) {
        int row = rr + p * 32;
        *(bf16x8*)(&K_lds[cur ^ 1][row * 72 + cc * 8]) = kreg2[p];
#pragma unroll
        for (int j = 0; j < 8; j++) {
          int d = cc * 8 + j;
          int byt = (d * 72 + row) * 2;
          byt ^= ((d >> 3) & 7) << 4;
          *(unsigned short*)((char*)&V_lds[cur ^ 1][0] + byt) = (unsigned short)vreg2[p][j];
        }
      }
    }
  }

  // epilogue: O / l per group
#pragma unroll
  for (int g = 0; g < 2; g++) {
    float inv[4];
#pragma unroll
    for (int r = 0; r < 4; r++) inv[r] = 1.0f / bperm_f(badr[r], l_r[g]);
    float* op = out + (size_t)(b * S_ + q0 + w * 32 + g * 16) * D_ + h * DH_;
#pragma unroll
    for (int dn = 0; dn < 4; dn++)
#pragma unroll
      for (int r = 0; r < 4; r++)
        op[(size_t)(lg * 4 + r) * D_ + dn * 16 + l15] = o_acc[g][dn][r] * inv[r];
  }
}

// ---------------- host launch ----------------
extern "C" void kernel_launch(void* const* d_in, const int* in_sizes, int n_in,
                              void* d_out, int out_size, void* d_ws, size_t ws_size,
                              hipStream_t stream) {
  const float* q = (const float*)d_in[0];
  const float* k = (const float*)d_in[1];
  const float* v = (const float*)d_in[2];
  const float* mask = (const float*)d_in[3];
  const float* Wq = (const float*)d_in[4];
  const float* Wk = (const float*)d_in[5];
  const float* Wv = (const float*)d_in[6];

  // ws: qh 16.78M | kh 16.78M | vh 16.78M | Wt 6.29M
  char* ws = (char*)d_ws;
  const size_t SZ_PROJ = (size_t)B_ * S_ * D_ * 2;
  unsigned short* qh = (unsigned short*)(ws);
  unsigned short* kh = (unsigned short*)(ws + SZ_PROJ);
  unsigned short* vh = (unsigned short*)(ws + 2 * SZ_PROJ);
  unsigned short* Wt = (unsigned short*)(ws + 3 * SZ_PROJ);

  wtrans_kernel<<<dim3(D_ / 32, D_ / 32, 3), dim3(32, 8), 0, stream>>>(Wq, Wk, Wv, Wt);
  proj_kernel<<<dim3(D_ / 128, (B_ * S_) / 128, 3), 256, 0, stream>>>(q, k, v, Wt, qh);
  attn_kernel<<<dim3(S_ / 128, H_, B_), 256, 0, stream>>>(qh, kh, vh, mask, (float*)d_out);
}